// Round 1
// baseline (237.325 us; speedup 1.0000x reference)
//
#include <hip/hip_runtime.h>
#include <math.h>

// Problem dims
#define NB  32
#define NT  200
#define NTQ 50
#define NE  64
#define NP  128
#define NC  64
#define NU  36

// ---------------------------------------------------------------------------
// Kernel 1: precompute per-(b,t) and per-(b,tq) partial projections.
//   qW[b,t,u]  = b1[u] + sum_e UB[b,t,e] * (W1[e,u] + W1[128+e,u])
//   kW[b,tq,u] =         sum_e IT[b,tq,e] * (W1[64+e,u] - W1[128+e,u])
// ---------------------------------------------------------------------------
__global__ void precompute_qk(const float* __restrict__ ub,
                              const float* __restrict__ it,
                              const float* __restrict__ W1,
                              const float* __restrict__ b1,
                              float* __restrict__ qW,
                              float* __restrict__ kW) {
    const int NQ = NB * NT * NU;
    const int NK = NB * NTQ * NU;
    int idx = blockIdx.x * 256 + threadIdx.x;
    if (idx < NQ) {
        int u = idx % NU;
        int row = idx / NU;     // b*NT + t
        const float* q = ub + row * NE;
        float acc = b1[u];
        #pragma unroll 4
        for (int e = 0; e < NE; ++e) {
            float w = W1[e * NU + u] + W1[(128 + e) * NU + u];
            acc = fmaf(q[e], w, acc);
        }
        qW[idx] = acc;
    } else if (idx < NQ + NK) {
        int j = idx - NQ;
        int u = j % NU;
        int row = j / NU;       // b*NTQ + tq
        const float* k = it + row * NE;
        float acc = 0.f;
        #pragma unroll 4
        for (int e = 0; e < NE; ++e) {
            float w = W1[(64 + e) * NU + u] - W1[(128 + e) * NU + u];
            acc = fmaf(k[e], w, acc);
        }
        kW[j] = acc;
    }
}

// ---------------------------------------------------------------------------
// Kernel 2: per (b,tq) block — cross-term attention MLP + dice + W2,
// interest reduction, and fused trunk MLP.
// ---------------------------------------------------------------------------
struct DinParams {
    const float *ub, *it, *up, *cx;
    const float *W1, *dice_alpha, *dice_mean, *dice_var, *W2, *b2;
    const float *bn1_g, *bn1_b, *bn1_m, *bn1_v, *Wm1, *bm1;
    const float *bn2_g, *bn2_b, *bn2_m, *bn2_v, *Wm2, *bm2;
    const float *bn3_g, *bn3_b, *bn3_m, *bn3_v, *Wm3, *bm3;
    const float *qW, *kW;
    float *out;
};

__global__ __launch_bounds__(256) void din_main(DinParams P) {
    // LDS: UB tile padded (stride 65 -> conflict-free for both row-wise and
    // column-wise access), plus small buffers. Total 55.1 KB -> 2 blocks/CU.
    __shared__ float ub_s[NT * 65];
    __shared__ float w_s[NT];
    __shared__ float k_s[NE];
    __shared__ float h_s[256];
    __shared__ float h2_s[256];

    const int tid = threadIdx.x;
    const int tq  = blockIdx.x;
    const int b   = blockIdx.y;

    // stage UB[b] (200x64) into LDS, coalesced
    const float* ubg = P.ub + (size_t)b * NT * NE;
    for (int i = tid; i < NT * NE; i += 256) {
        int t = i >> 6, e = i & 63;
        ub_s[t * 65 + e] = ubg[i];
    }
    if (tid < NE) k_s[tid] = P.it[((size_t)b * NTQ + tq) * NE + tid];
    __syncthreads();

    // ---- phase A: attention weight per history step t ----
    if (tid < NT) {
        const int t = tid;
        float acc[NU];
        const float* qw = P.qW + ((size_t)b * NT + t) * NU;
        const float* kw = P.kW + ((size_t)b * NTQ + tq) * NU;
        #pragma unroll
        for (int u = 0; u < NU; ++u) acc[u] = qw[u] + kw[u];

        const float* wp = P.W1 + 192 * NU;   // W1 rows 192..255 (the q*k block)
        #pragma unroll 2
        for (int e = 0; e < NE; ++e) {
            float qk = ub_s[t * 65 + e] * k_s[e];
            #pragma unroll
            for (int u = 0; u < NU; ++u)
                acc[u] = fmaf(qk, wp[e * NU + u], acc[u]);
        }

        // dice + W2 dot
        float wsum = P.b2[0];
        #pragma unroll
        for (int u = 0; u < NU; ++u) {
            float x = acc[u];
            float z = (x - P.dice_mean[u]) * rsqrtf(P.dice_var[u] + 1e-6f);
            float p = 1.f / (1.f + __expf(-z));
            float a = P.dice_alpha[u];
            wsum = fmaf(x * (a + p * (1.f - a)), P.W2[u], wsum);
        }
        w_s[t] = wsum;
    }
    __syncthreads();

    // ---- phase B: interest = sum_t w[t] * UB[b,t,:], concat profile/context ----
    if (tid < NE) {
        float s = 0.f;
        #pragma unroll 8
        for (int t = 0; t < NT; ++t)
            s = fmaf(w_s[t], ub_s[t * 65 + tid], s);
        h_s[tid] = s;
    } else if (tid < NE + NP) {
        h_s[tid] = P.up[(size_t)b * NP + (tid - NE)];
    } else {
        h_s[tid] = P.cx[(size_t)b * NC + (tid - NE - NP)];
    }
    __syncthreads();

    // ---- phase C: trunk MLP ----
    // BN1
    float hn = (h_s[tid] - P.bn1_m[tid]) * rsqrtf(P.bn1_v[tid] + 1e-6f)
               * P.bn1_g[tid] + P.bn1_b[tid];
    h2_s[tid] = hn;                 // h2_s first use; no pending readers
    __syncthreads();

    // layer 1: 256 -> 256, relu, then BN2
    {
        float o = P.bm1[tid];
        #pragma unroll 8
        for (int f = 0; f < 256; ++f)
            o = fmaf(h2_s[f], P.Wm1[f * 256 + tid], o);
        o = fmaxf(o, 0.f);
        float on = (o - P.bn2_m[tid]) * rsqrtf(P.bn2_v[tid] + 1e-6f)
                   * P.bn2_g[tid] + P.bn2_b[tid];
        h_s[tid] = on;              // h_s has no pending readers (only own-elem reads pre-barrier)
    }
    __syncthreads();

    // layer 2: 256 -> 128, relu, then BN3
    if (tid < 128) {
        float o = P.bm2[tid];
        #pragma unroll 8
        for (int f = 0; f < 256; ++f)
            o = fmaf(h_s[f], P.Wm2[f * 128 + tid], o);
        o = fmaxf(o, 0.f);
        float on = (o - P.bn3_m[tid]) * rsqrtf(P.bn3_v[tid] + 1e-6f)
                   * P.bn3_g[tid] + P.bn3_b[tid];
        h2_s[tid] = on;             // all layer-1 reads of h2_s completed at barrier above
    }
    __syncthreads();

    // layer 3: 128 -> 64, relu, write out
    if (tid < 64) {
        float o = P.bm3[tid];
        #pragma unroll 8
        for (int f = 0; f < 128; ++f)
            o = fmaf(h2_s[f], P.Wm3[f * 64 + tid], o);
        P.out[((size_t)b * NTQ + tq) * NE + tid] = fmaxf(o, 0.f);
    }
}

// ---------------------------------------------------------------------------
extern "C" void kernel_launch(void* const* d_in, const int* in_sizes, int n_in,
                              void* d_out, int out_size, void* d_ws, size_t ws_size,
                              hipStream_t stream) {
    (void)in_sizes; (void)n_in; (void)out_size; (void)ws_size;

    const float* ub         = (const float*)d_in[0];
    const float* it         = (const float*)d_in[1];
    const float* up         = (const float*)d_in[2];
    const float* cx         = (const float*)d_in[3];
    const float* W1         = (const float*)d_in[4];
    const float* b1         = (const float*)d_in[5];
    const float* dice_alpha = (const float*)d_in[6];
    const float* dice_mean  = (const float*)d_in[7];
    const float* dice_var   = (const float*)d_in[8];
    const float* W2         = (const float*)d_in[9];
    const float* b2         = (const float*)d_in[10];
    const float* bn1_g      = (const float*)d_in[11];
    const float* bn1_b      = (const float*)d_in[12];
    const float* bn1_m      = (const float*)d_in[13];
    const float* bn1_v      = (const float*)d_in[14];
    const float* Wm1        = (const float*)d_in[15];
    const float* bm1        = (const float*)d_in[16];
    const float* bn2_g      = (const float*)d_in[17];
    const float* bn2_b      = (const float*)d_in[18];
    const float* bn2_m      = (const float*)d_in[19];
    const float* bn2_v      = (const float*)d_in[20];
    const float* Wm2        = (const float*)d_in[21];
    const float* bm2        = (const float*)d_in[22];
    const float* bn3_g      = (const float*)d_in[23];
    const float* bn3_b      = (const float*)d_in[24];
    const float* bn3_m      = (const float*)d_in[25];
    const float* bn3_v      = (const float*)d_in[26];
    const float* Wm3        = (const float*)d_in[27];
    const float* bm3        = (const float*)d_in[28];

    float* qW = (float*)d_ws;                  // NB*NT*NU  = 230400 floats
    float* kW = qW + (size_t)NB * NT * NU;     // NB*NTQ*NU =  57600 floats

    {
        const int total = NB * NT * NU + NB * NTQ * NU;   // 288000
        precompute_qk<<<(total + 255) / 256, 256, 0, stream>>>(ub, it, W1, b1, qW, kW);
    }

    DinParams P;
    P.ub = ub; P.it = it; P.up = up; P.cx = cx;
    P.W1 = W1; P.dice_alpha = dice_alpha; P.dice_mean = dice_mean; P.dice_var = dice_var;
    P.W2 = W2; P.b2 = b2;
    P.bn1_g = bn1_g; P.bn1_b = bn1_b; P.bn1_m = bn1_m; P.bn1_v = bn1_v; P.Wm1 = Wm1; P.bm1 = bm1;
    P.bn2_g = bn2_g; P.bn2_b = bn2_b; P.bn2_m = bn2_m; P.bn2_v = bn2_v; P.Wm2 = Wm2; P.bm2 = bm2;
    P.bn3_g = bn3_g; P.bn3_b = bn3_b; P.bn3_m = bn3_m; P.bn3_v = bn3_v; P.Wm3 = Wm3; P.bm3 = bm3;
    P.qW = qW; P.kW = kW;
    P.out = (float*)d_out;

    din_main<<<dim3(NTQ, NB), 256, 0, stream>>>(P);
}

// Round 2
// 188.134 us; speedup vs baseline: 1.2615x; 1.2615x over previous
//
#include <hip/hip_runtime.h>
#include <hip/hip_bf16.h>
#include <math.h>

#define NB  32
#define NT  200
#define NTQ 50
#define NE  64
#define NP  128
#define NC  64
#define NU  36
#define NROW (NB * NTQ)   // 1600

typedef __attribute__((ext_vector_type(8))) short bf8;   // 8 bf16 in 4 VGPRs
typedef __attribute__((ext_vector_type(4))) float f4;

// ---- ws layout ----
// f32 region:
//   qW  : [NB*NT*NU]  = 230400   @ 0
//   kW  : [NB*NTQ*NU] =  57600   @ 230400
// bf16 region (base = 288000 f32 elems):
//   w1df: [3][2][64][8]          @ 0       (3072)
//   wm1f: [16*8][64][8]          @ 3072    (65536)
//   wm2f: [8*8][64][8]           @ 68608   (32768)
//   wm3f: [4*4][64][8]           @ 101376  (8192)
//   Hh  : [1600][256]            @ 109568  (409600)
#define QW_F32   0
#define KW_F32   230400
#define BF_BASE  288000
#define W1DF_OFF 0
#define WM1F_OFF 3072
#define WM2F_OFF 68608
#define WM3F_OFF 101376
#define HH_OFF   109568

__device__ __forceinline__ short f2bf(float x) {
    __hip_bfloat16 h = __float2bfloat16(x);
    return __builtin_bit_cast(short, h);
}
__device__ __forceinline__ float bf2f(short s) {
    unsigned u = ((unsigned)(unsigned short)s) << 16;
    return __builtin_bit_cast(float, u);
}

// ---------------------------------------------------------------------------
// Kernel P: all precompute. Flat index over 7 jobs.
// ---------------------------------------------------------------------------
__device__ __forceinline__ void pack_frag(int j, const float* W, int N, int ksc, short* dst) {
    int i    = j & 7;
    int lane = (j >> 3) & 63;
    int tile = j >> 9;
    int ks = tile % ksc;
    int nt = tile / ksc;
    int k = ks * 32 + 8 * (lane >> 4) + i;     // B[k][n]: k = 8*(l>>4)+i within K=32
    int n = nt * 16 + (lane & 15);
    dst[j] = f2bf(W[k * N + n]);
}

__global__ __launch_bounds__(256) void prep(
    const float* __restrict__ ub, const float* __restrict__ it,
    const float* __restrict__ up, const float* __restrict__ cx,
    const float* __restrict__ W1, const float* __restrict__ b1,
    const float* __restrict__ Wm1, const float* __restrict__ Wm2, const float* __restrict__ Wm3,
    const float* __restrict__ bn1_g, const float* __restrict__ bn1_b,
    const float* __restrict__ bn1_m, const float* __restrict__ bn1_v,
    float* __restrict__ qW, float* __restrict__ kW,
    short* __restrict__ w1df, short* __restrict__ wm1f,
    short* __restrict__ wm2f, short* __restrict__ wm3f, short* __restrict__ Hh)
{
    int idx = blockIdx.x * 256 + threadIdx.x;
    if (idx < NB * NT * NU) {                       // J1: qW
        int u = idx % NU, row = idx / NU;
        const float* q = ub + row * NE;
        float acc = b1[u];
        #pragma unroll 4
        for (int e = 0; e < NE; ++e)
            acc = fmaf(q[e], W1[e * NU + u] + W1[(128 + e) * NU + u], acc);
        qW[idx] = acc;
        return;
    }
    idx -= NB * NT * NU;
    if (idx < NB * NTQ * NU) {                      // J2: kW
        int u = idx % NU, row = idx / NU;
        const float* k = it + row * NE;
        float acc = 0.f;
        #pragma unroll 4
        for (int e = 0; e < NE; ++e)
            acc = fmaf(k[e], W1[(64 + e) * NU + u] - W1[(128 + e) * NU + u], acc);
        kW[idx] = acc;
        return;
    }
    idx -= NB * NTQ * NU;
    if (idx < 3072) {                               // J3: W1d frags (u padded to 48)
        int i = idx & 7, lane = (idx >> 3) & 63, tile = idx >> 9;
        int ks = tile % 2, nt = tile / 2;
        int k = ks * 32 + 8 * (lane >> 4) + i;      // e in 0..63
        int n = nt * 16 + (lane & 15);              // u in 0..47
        w1df[idx] = (n < NU) ? f2bf(W1[(192 + k) * NU + n]) : (short)0;
        return;
    }
    idx -= 3072;
    if (idx < 65536) { pack_frag(idx, Wm1, 256, 8, wm1f); return; }
    idx -= 65536;
    if (idx < 32768) { pack_frag(idx, Wm2, 128, 8, wm2f); return; }
    idx -= 32768;
    if (idx < 8192)  { pack_frag(idx, Wm3,  64, 4, wm3f); return; }
    idx -= 8192;
    if (idx < NROW * 192) {                         // J7: Hh cols 64..255 = bn1(profile||context)
        int row = idx / 192, c = idx % 192;
        int col = 64 + c, b = row / NTQ;
        float val = (c < NP) ? up[b * NP + c] : cx[b * NC + (c - NP)];
        float hn = (val - bn1_m[col]) * rsqrtf(bn1_v[col] + 1e-6f) * bn1_g[col] + bn1_b[col];
        Hh[row * 256 + col] = f2bf(hn);
    }
}

// ---------------------------------------------------------------------------
// Kernel A: attention (MFMA cross-term, split-bf16 A) + interest + BN1 -> Hh[:,0:64]
// One block per (tq, b). 4 waves; wave w handles t-tiles w, w+4, w+8, w+12.
// ---------------------------------------------------------------------------
struct AParams {
    const float *ub, *it, *qW, *kW, *W2, *b2, *da, *dm, *dv;
    const float *bn1_g, *bn1_b, *bn1_m, *bn1_v;
    const short *w1df;
    short* Hh;
};

__global__ __launch_bounds__(256) void attn(AParams P) {
    __shared__ float w_s[NT];
    __shared__ float red_s[256];

    const int tid = threadIdx.x;
    const int l = tid & 63, w = tid >> 6;
    const int tq = blockIdx.x, b = blockIdx.y;

    // B-fragments of W1d: loaded once, live in registers for all tiles.
    bf8 bfr[3][2];
    {
        const bf8* wf = (const bf8*)P.w1df;
        #pragma unroll
        for (int nt = 0; nt < 3; ++nt)
            #pragma unroll
            for (int ks = 0; ks < 2; ++ks)
                bfr[nt][ks] = wf[(nt * 2 + ks) * 64 + l];
    }

    // this lane's it[e] values (A-frag k positions): e = ks*32 + 8*(l>>4) + i
    float itv[2][8];
    {
        const float* itr = P.it + ((size_t)b * NTQ + tq) * NE;
        #pragma unroll
        for (int ks = 0; ks < 2; ++ks) {
            int e0 = ks * 32 + 8 * (l >> 4);
            f4 v0 = *(const f4*)(itr + e0);
            f4 v1 = *(const f4*)(itr + e0 + 4);
            #pragma unroll
            for (int i = 0; i < 4; ++i) { itv[ks][i] = v0[i]; itv[ks][4 + i] = v1[i]; }
        }
    }

    // per-u (output column) constants for this lane
    const int ul = l & 15;
    float kwv[3], dmv[3], drs[3], dav[3], w2v[3];
    {
        const float* kwr = P.kW + ((size_t)b * NTQ + tq) * NU;
        #pragma unroll
        for (int nt = 0; nt < 3; ++nt) {
            int u = nt * 16 + ul;
            bool v = (u < NU);
            int uc = v ? u : (NU - 1);
            kwv[nt] = v ? kwr[uc] : 0.f;
            dmv[nt] = P.dm[uc];
            drs[nt] = rsqrtf(P.dv[uc] + 1e-6f);
            dav[nt] = P.da[uc];
            w2v[nt] = v ? P.W2[uc] : 0.f;
        }
    }
    const float b2s = P.b2[0];

    const float* qwr = P.qW + (size_t)b * NT * NU;

    for (int tt = w; tt < 13; tt += 4) {
        const int t0 = tt * 16;
        const int tA = t0 + (l & 15);           // A-frag row

        bf8 ah[2], al[2];
        if (tA < NT) {
            const float* ubr = P.ub + ((size_t)b * NT + tA) * NE;
            #pragma unroll
            for (int ks = 0; ks < 2; ++ks) {
                int e0 = ks * 32 + 8 * (l >> 4);
                f4 u0 = *(const f4*)(ubr + e0);
                f4 u1 = *(const f4*)(ubr + e0 + 4);
                #pragma unroll
                for (int i = 0; i < 4; ++i) {
                    float q0 = u0[i] * itv[ks][i];
                    short h0 = f2bf(q0);
                    ah[ks][i] = h0;
                    al[ks][i] = f2bf(q0 - bf2f(h0));
                    float q1 = u1[i] * itv[ks][4 + i];
                    short h1 = f2bf(q1);
                    ah[ks][4 + i] = h1;
                    al[ks][4 + i] = f2bf(q1 - bf2f(h1));
                }
            }
        } else {
            #pragma unroll
            for (int ks = 0; ks < 2; ++ks)
                #pragma unroll
                for (int i = 0; i < 8; ++i) { ah[ks][i] = 0; al[ks][i] = 0; }
        }

        f4 acc[3];
        #pragma unroll
        for (int nt = 0; nt < 3; ++nt) { acc[nt][0]=0.f; acc[nt][1]=0.f; acc[nt][2]=0.f; acc[nt][3]=0.f; }
        #pragma unroll
        for (int nt = 0; nt < 3; ++nt)
            #pragma unroll
            for (int ks = 0; ks < 2; ++ks) {
                acc[nt] = __builtin_amdgcn_mfma_f32_16x16x32_bf16(ah[ks], bfr[nt][ks], acc[nt], 0, 0, 0);
                acc[nt] = __builtin_amdgcn_mfma_f32_16x16x32_bf16(al[ks], bfr[nt][ks], acc[nt], 0, 0, 0);
            }

        // epilogue: D row = t0 + 4*(l>>4) + i, col u = nt*16 + (l&15)
        const int tD = t0 + 4 * (l >> 4);
        #pragma unroll
        for (int i = 0; i < 4; ++i) {
            int t = tD + i;
            bool tv = (t < NT);
            int tc = tv ? t : (NT - 1);
            float val = 0.f;
            #pragma unroll
            for (int nt = 0; nt < 3; ++nt) {
                int u = nt * 16 + ul;
                int uc = (u < NU) ? u : (NU - 1);
                float x = acc[nt][i] + qwr[tc * NU + uc] + kwv[nt];
                float z = (x - dmv[nt]) * drs[nt];
                float p = 1.f / (1.f + __expf(-z));
                val += x * (dav[nt] + p * (1.f - dav[nt])) * w2v[nt];
            }
            val += __shfl_xor(val, 1);
            val += __shfl_xor(val, 2);
            val += __shfl_xor(val, 4);
            val += __shfl_xor(val, 8);
            if (ul == 0 && tv) w_s[t] = val + b2s;
        }
    }
    __syncthreads();

    // interest[e] = sum_t w[t]*ub[b,t,e]; then BN1; write bf16 H row cols 0..63
    {
        const int e = tid & 63, g = tid >> 6;
        const float* ubb = P.ub + (size_t)b * NT * NE;
        float s = 0.f;
        #pragma unroll 5
        for (int t = g * 50; t < g * 50 + 50; ++t)
            s = fmaf(w_s[t], ubb[t * NE + e], s);
        red_s[tid] = s;
    }
    __syncthreads();
    if (tid < 64) {
        float tot = red_s[tid] + red_s[64 + tid] + red_s[128 + tid] + red_s[192 + tid];
        float hn = (tot - P.bn1_m[tid]) * rsqrtf(P.bn1_v[tid] + 1e-6f) * P.bn1_g[tid] + P.bn1_b[tid];
        P.Hh[((size_t)b * NTQ + tq) * 256 + tid] = f2bf(hn);
    }
}

// ---------------------------------------------------------------------------
// Kernel T: batched trunk MLP over 1600 rows. Block = 32 rows, 4 waves:
// wave (mt = w&1) -> 16-row m-tile, (nh = w>>1) -> N half. MFMA bf16.
// ---------------------------------------------------------------------------
struct TParams {
    const short *Hh, *wm1f, *wm2f, *wm3f;
    const float *bm1, *bm2, *bm3;
    const float *bn2_g, *bn2_b, *bn2_m, *bn2_v;
    const float *bn3_g, *bn3_b, *bn3_m, *bn3_v;
    float* out;
};

#define LSTR 264   // bf16 row stride: 528B -> >=2-way max bank aliasing (free)

__global__ __launch_bounds__(256) void trunk(TParams P) {
    __shared__ short Ha[32 * LSTR];
    __shared__ short Hb[32 * LSTR];

    const int tid = threadIdx.x;
    const int l = tid & 63, w = tid >> 6;
    const int mt = w & 1, nh = w >> 1;
    const int row0 = blockIdx.x * 32;

    // stage 32x256 bf16 rows of Hh into Ha
    {
        const bf8* src = (const bf8*)(P.Hh + (size_t)row0 * 256);
        for (int ch = tid; ch < 32 * 32; ch += 256) {
            int r = ch >> 5, c8 = ch & 31;
            *(bf8*)&Ha[r * LSTR + c8 * 8] = src[r * 32 + c8];
        }
    }
    __syncthreads();

    const int ar = mt * 16 + (l & 15);          // A-frag row (local)
    const int rl = mt * 16 + 4 * (l >> 4);      // D row base (local)
    const int nl = l & 15;                      // D col within n-tile

    // ---- layer 1: K=256, N=256 : Ha -> Hb, relu then BN2 ----
    {
        bf8 a[8];
        #pragma unroll
        for (int ks = 0; ks < 8; ++ks)
            a[ks] = *(const bf8*)&Ha[ar * LSTR + ks * 32 + 8 * (l >> 4)];
        const bf8* wf = (const bf8*)P.wm1f;
        #pragma unroll
        for (int nt0 = 0; nt0 < 8; ++nt0) {
            int nt = nh * 8 + nt0;
            f4 acc; acc[0]=0.f; acc[1]=0.f; acc[2]=0.f; acc[3]=0.f;
            #pragma unroll
            for (int ks = 0; ks < 8; ++ks)
                acc = __builtin_amdgcn_mfma_f32_16x16x32_bf16(a[ks], wf[(nt * 8 + ks) * 64 + l], acc, 0, 0, 0);
            int n = nt * 16 + nl;
            float g1 = P.bn2_g[n] * rsqrtf(P.bn2_v[n] + 1e-6f);
            float c1 = P.bn2_b[n] - P.bn2_m[n] * g1;
            float bias = P.bm1[n];
            #pragma unroll
            for (int i = 0; i < 4; ++i) {
                float v = fmaxf(acc[i] + bias, 0.f);
                Hb[(rl + i) * LSTR + n] = f2bf(v * g1 + c1);
            }
        }
    }
    __syncthreads();

    // ---- layer 2: K=256, N=128 : Hb -> Ha[:,0:128], relu then BN3 ----
    {
        bf8 a[8];
        #pragma unroll
        for (int ks = 0; ks < 8; ++ks)
            a[ks] = *(const bf8*)&Hb[ar * LSTR + ks * 32 + 8 * (l >> 4)];
        const bf8* wf = (const bf8*)P.wm2f;
        #pragma unroll
        for (int nt0 = 0; nt0 < 4; ++nt0) {
            int nt = nh * 4 + nt0;
            f4 acc; acc[0]=0.f; acc[1]=0.f; acc[2]=0.f; acc[3]=0.f;
            #pragma unroll
            for (int ks = 0; ks < 8; ++ks)
                acc = __builtin_amdgcn_mfma_f32_16x16x32_bf16(a[ks], wf[(nt * 8 + ks) * 64 + l], acc, 0, 0, 0);
            int n = nt * 16 + nl;
            float g1 = P.bn3_g[n] * rsqrtf(P.bn3_v[n] + 1e-6f);
            float c1 = P.bn3_b[n] - P.bn3_m[n] * g1;
            float bias = P.bm2[n];
            #pragma unroll
            for (int i = 0; i < 4; ++i) {
                float v = fmaxf(acc[i] + bias, 0.f);
                Ha[(rl + i) * LSTR + n] = f2bf(v * g1 + c1);
            }
        }
    }
    __syncthreads();

    // ---- layer 3: K=128, N=64 : Ha[:,0:128] -> out, relu ----
    {
        bf8 a[4];
        #pragma unroll
        for (int ks = 0; ks < 4; ++ks)
            a[ks] = *(const bf8*)&Ha[ar * LSTR + ks * 32 + 8 * (l >> 4)];
        const bf8* wf = (const bf8*)P.wm3f;
        #pragma unroll
        for (int nt0 = 0; nt0 < 2; ++nt0) {
            int nt = nh * 2 + nt0;
            f4 acc; acc[0]=0.f; acc[1]=0.f; acc[2]=0.f; acc[3]=0.f;
            #pragma unroll
            for (int ks = 0; ks < 4; ++ks)
                acc = __builtin_amdgcn_mfma_f32_16x16x32_bf16(a[ks], wf[(nt * 4 + ks) * 64 + l], acc, 0, 0, 0);
            int n = nt * 16 + nl;
            float bias = P.bm3[n];
            #pragma unroll
            for (int i = 0; i < 4; ++i)
                P.out[(size_t)(row0 + rl + i) * 64 + n] = fmaxf(acc[i] + bias, 0.f);
        }
    }
}

// ---------------------------------------------------------------------------
extern "C" void kernel_launch(void* const* d_in, const int* in_sizes, int n_in,
                              void* d_out, int out_size, void* d_ws, size_t ws_size,
                              hipStream_t stream) {
    (void)in_sizes; (void)n_in; (void)out_size; (void)ws_size;

    const float* ub         = (const float*)d_in[0];
    const float* it         = (const float*)d_in[1];
    const float* up         = (const float*)d_in[2];
    const float* cx         = (const float*)d_in[3];
    const float* W1         = (const float*)d_in[4];
    const float* b1         = (const float*)d_in[5];
    const float* dice_alpha = (const float*)d_in[6];
    const float* dice_mean  = (const float*)d_in[7];
    const float* dice_var   = (const float*)d_in[8];
    const float* W2         = (const float*)d_in[9];
    const float* b2         = (const float*)d_in[10];
    const float* bn1_g      = (const float*)d_in[11];
    const float* bn1_b      = (const float*)d_in[12];
    const float* bn1_m      = (const float*)d_in[13];
    const float* bn1_v      = (const float*)d_in[14];
    const float* Wm1        = (const float*)d_in[15];
    const float* bm1        = (const float*)d_in[16];
    const float* bn2_g      = (const float*)d_in[17];
    const float* bn2_b      = (const float*)d_in[18];
    const float* bn2_m      = (const float*)d_in[19];
    const float* bn2_v      = (const float*)d_in[20];
    const float* Wm2        = (const float*)d_in[21];
    const float* bm2        = (const float*)d_in[22];
    const float* bn3_g      = (const float*)d_in[23];
    const float* bn3_b      = (const float*)d_in[24];
    const float* bn3_m      = (const float*)d_in[25];
    const float* bn3_v      = (const float*)d_in[26];
    const float* Wm3        = (const float*)d_in[27];
    const float* bm3        = (const float*)d_in[28];

    float* qW  = (float*)d_ws + QW_F32;
    float* kW  = (float*)d_ws + KW_F32;
    short* wsb = (short*)((float*)d_ws + BF_BASE);
    short* w1df = wsb + W1DF_OFF;
    short* wm1f = wsb + WM1F_OFF;
    short* wm2f = wsb + WM2F_OFF;
    short* wm3f = wsb + WM3F_OFF;
    short* Hh   = wsb + HH_OFF;

    const int prep_total = 704768;
    prep<<<(prep_total + 255) / 256, 256, 0, stream>>>(
        ub, it, up, cx, W1, b1, Wm1, Wm2, Wm3,
        bn1_g, bn1_b, bn1_m, bn1_v,
        qW, kW, w1df, wm1f, wm2f, wm3f, Hh);

    AParams A;
    A.ub = ub; A.it = it; A.qW = qW; A.kW = kW;
    A.W2 = W2; A.b2 = b2; A.da = dice_alpha; A.dm = dice_mean; A.dv = dice_var;
    A.bn1_g = bn1_g; A.bn1_b = bn1_b; A.bn1_m = bn1_m; A.bn1_v = bn1_v;
    A.w1df = w1df; A.Hh = Hh;
    attn<<<dim3(NTQ, NB), 256, 0, stream>>>(A);

    TParams T;
    T.Hh = Hh; T.wm1f = wm1f; T.wm2f = wm2f; T.wm3f = wm3f;
    T.bm1 = bm1; T.bm2 = bm2; T.bm3 = bm3;
    T.bn2_g = bn2_g; T.bn2_b = bn2_b; T.bn2_m = bn2_m; T.bn2_v = bn2_v;
    T.bn3_g = bn3_g; T.bn3_b = bn3_b; T.bn3_m = bn3_m; T.bn3_v = bn3_v;
    T.out = (float*)d_out;
    trunk<<<NROW / 32, 256, 0, stream>>>(T);
}

// Round 3
// 183.459 us; speedup vs baseline: 1.2936x; 1.0255x over previous
//
#include <hip/hip_runtime.h>
#include <hip/hip_bf16.h>
#include <math.h>

#define NB  32
#define NT  200
#define NTQ 50
#define NE  64
#define NP  128
#define NC  64
#define NU  36
#define NROW (NB * NTQ)   // 1600

typedef __attribute__((ext_vector_type(8))) short bf8;   // 8 bf16 in 4 VGPRs
typedef __attribute__((ext_vector_type(4))) float f4;

// ---- ws layout ----
// f32 region:
//   kW  : [NB*NTQ*NU] = 57600    @ 0   (includes b1)
// bf16 region (base = 57600 f32 elems):
//   w1f : [3][4][64][8]          @ 0       (6144)   extended-K B frags
//   wm1f: [16*8][64][8]          @ 6144    (65536)
//   wm2f: [8*8][64][8]           @ 71680   (32768)
//   wm3f: [4*4][64][8]           @ 104448  (8192)
//   Hh  : [1600][256]            @ 112640  (409600)
#define KW_F32   0
#define BF_BASE  57600
#define W1F_OFF  0
#define WM1F_OFF 6144
#define WM2F_OFF 71680
#define WM3F_OFF 104448
#define HH_OFF   112640

__device__ __forceinline__ short f2bf(float x) {
    __hip_bfloat16 h = __float2bfloat16(x);
    return __builtin_bit_cast(short, h);
}

// ---------------------------------------------------------------------------
// Kernel P: precompute. Flat index over jobs:
//   J2: kW (57600) -- k@(W1b-W1c) + b1
//   J3: w1f (6144) -- extended-K [ (W1a+W1c) ; W1d ] fragments (u padded to 48)
//   J4/5/6: trunk weight fragments
//   J7: Hh cols 64..255 = bn1(profile || context)
// ---------------------------------------------------------------------------
__device__ __forceinline__ void pack_frag(int j, const float* W, int N, int ksc, short* dst) {
    int i    = j & 7;
    int lane = (j >> 3) & 63;
    int tile = j >> 9;
    int ks = tile % ksc;
    int nt = tile / ksc;
    int k = ks * 32 + 8 * (lane >> 4) + i;
    int n = nt * 16 + (lane & 15);
    dst[j] = f2bf(W[k * N + n]);
}

__global__ __launch_bounds__(256) void prep(
    const float* __restrict__ it,
    const float* __restrict__ up, const float* __restrict__ cx,
    const float* __restrict__ W1, const float* __restrict__ b1,
    const float* __restrict__ Wm1, const float* __restrict__ Wm2, const float* __restrict__ Wm3,
    const float* __restrict__ bn1_g, const float* __restrict__ bn1_b,
    const float* __restrict__ bn1_m, const float* __restrict__ bn1_v,
    float* __restrict__ kW,
    short* __restrict__ w1f, short* __restrict__ wm1f,
    short* __restrict__ wm2f, short* __restrict__ wm3f, short* __restrict__ Hh)
{
    int idx = blockIdx.x * 256 + threadIdx.x;
    if (idx < NB * NTQ * NU) {                      // J2: kW (+ b1)
        int u = idx % NU, row = idx / NU;
        const float* k = it + row * NE;
        float acc = b1[u];
        #pragma unroll 4
        for (int e = 0; e < NE; ++e)
            acc = fmaf(k[e], W1[(64 + e) * NU + u] - W1[(128 + e) * NU + u], acc);
        kW[idx] = acc;
        return;
    }
    idx -= NB * NTQ * NU;
    if (idx < 6144) {                               // J3: extended-K W1 frags
        int i = idx & 7, lane = (idx >> 3) & 63, tile = idx >> 9;
        int ks = tile & 3, nt = tile >> 2;
        int kk = ks * 32 + 8 * (lane >> 4) + i;     // 0..127
        int n  = nt * 16 + (lane & 15);             // u in 0..47
        float v = 0.f;
        if (n < NU) {
            v = W1[(128 + kk) * NU + n];            // kk<64: W1c ; kk>=64: W1d
            if (kk < 64) v += W1[kk * NU + n];      // + W1a
        }
        w1f[idx] = f2bf(v);
        return;
    }
    idx -= 6144;
    if (idx < 65536) { pack_frag(idx, Wm1, 256, 8, wm1f); return; }
    idx -= 65536;
    if (idx < 32768) { pack_frag(idx, Wm2, 128, 8, wm2f); return; }
    idx -= 32768;
    if (idx < 8192)  { pack_frag(idx, Wm3,  64, 4, wm3f); return; }
    idx -= 8192;
    if (idx < NROW * 192) {                         // J7: Hh cols 64..255
        int row = idx / 192, c = idx % 192;
        int col = 64 + c, b = row / NTQ;
        float val = (c < NP) ? up[b * NP + c] : cx[b * NC + (c - NP)];
        float hn = (val - bn1_m[col]) * rsqrtf(bn1_v[col] + 1e-6f) * bn1_g[col] + bn1_b[col];
        Hh[row * 256 + col] = f2bf(hn);
    }
}

// ---------------------------------------------------------------------------
// Kernel A: attention with extended-K MFMA (K=128: [q | q*k]) + dice + W2,
// interest reduction, BN1 -> Hh[:,0:64]. One block per (tq, b), 4 waves.
// ---------------------------------------------------------------------------
struct AParams {
    const float *ub, *it, *kW, *W2, *b2, *da, *dm, *dv;
    const float *bn1_g, *bn1_b, *bn1_m, *bn1_v;
    const short *w1f;
    short* Hh;
};

__global__ __launch_bounds__(256) void attn(AParams P) {
    __shared__ float w_s[NT];
    __shared__ float red_s[256];

    const int tid = threadIdx.x;
    const int l = tid & 63, w = tid >> 6;
    const int tq = blockIdx.x, b = blockIdx.y;

    // B-fragments (12 x bf8 = 48 VGPR), live for the whole kernel
    bf8 bfr[3][4];
    {
        const bf8* wf = (const bf8*)P.w1f;
        #pragma unroll
        for (int nt = 0; nt < 3; ++nt)
            #pragma unroll
            for (int ks = 0; ks < 4; ++ks)
                bfr[nt][ks] = wf[(nt * 4 + ks) * 64 + l];
    }

    // this lane's it[e] values at A-frag k positions: e = ks*32 + 8*(l>>4) + i
    float itv[2][8];
    {
        const float* itr = P.it + ((size_t)b * NTQ + tq) * NE;
        #pragma unroll
        for (int ks = 0; ks < 2; ++ks) {
            int e0 = ks * 32 + 8 * (l >> 4);
            f4 v0 = *(const f4*)(itr + e0);
            f4 v1 = *(const f4*)(itr + e0 + 4);
            #pragma unroll
            for (int i = 0; i < 4; ++i) { itv[ks][i] = v0[i]; itv[ks][4 + i] = v1[i]; }
        }
    }

    // per-u (output column) constants
    const int ul = l & 15;
    float kwv[3], dmv[3], drs[3], dav[3], w2v[3];
    {
        const float* kwr = P.kW + ((size_t)b * NTQ + tq) * NU;
        #pragma unroll
        for (int nt = 0; nt < 3; ++nt) {
            int u = nt * 16 + ul;
            bool v = (u < NU);
            int uc = v ? u : (NU - 1);
            kwv[nt] = v ? kwr[uc] : 0.f;
            dmv[nt] = P.dm[uc];
            drs[nt] = rsqrtf(P.dv[uc] + 1e-6f);
            dav[nt] = P.da[uc];
            w2v[nt] = v ? P.W2[uc] : 0.f;
        }
    }
    const float b2s = P.b2[0];

    for (int tt = w; tt < 13; tt += 4) {
        const int t0 = tt * 16;
        const int tA = t0 + (l & 15);           // A-frag row

        bf8 aq[2], ap[2];
        if (tA < NT) {
            const float* ubr = P.ub + ((size_t)b * NT + tA) * NE;
            #pragma unroll
            for (int ks = 0; ks < 2; ++ks) {
                int e0 = ks * 32 + 8 * (l >> 4);
                f4 u0 = *(const f4*)(ubr + e0);
                f4 u1 = *(const f4*)(ubr + e0 + 4);
                #pragma unroll
                for (int i = 0; i < 4; ++i) {
                    aq[ks][i]     = f2bf(u0[i]);
                    aq[ks][4 + i] = f2bf(u1[i]);
                    ap[ks][i]     = f2bf(u0[i] * itv[ks][i]);
                    ap[ks][4 + i] = f2bf(u1[i] * itv[ks][4 + i]);
                }
            }
        } else {
            #pragma unroll
            for (int ks = 0; ks < 2; ++ks)
                #pragma unroll
                for (int i = 0; i < 8; ++i) { aq[ks][i] = 0; ap[ks][i] = 0; }
        }

        f4 acc[3];
        #pragma unroll
        for (int nt = 0; nt < 3; ++nt) { acc[nt][0]=0.f; acc[nt][1]=0.f; acc[nt][2]=0.f; acc[nt][3]=0.f; }
        #pragma unroll
        for (int nt = 0; nt < 3; ++nt) {
            acc[nt] = __builtin_amdgcn_mfma_f32_16x16x32_bf16(aq[0], bfr[nt][0], acc[nt], 0, 0, 0);
            acc[nt] = __builtin_amdgcn_mfma_f32_16x16x32_bf16(aq[1], bfr[nt][1], acc[nt], 0, 0, 0);
            acc[nt] = __builtin_amdgcn_mfma_f32_16x16x32_bf16(ap[0], bfr[nt][2], acc[nt], 0, 0, 0);
            acc[nt] = __builtin_amdgcn_mfma_f32_16x16x32_bf16(ap[1], bfr[nt][3], acc[nt], 0, 0, 0);
        }

        // epilogue: D row = t0 + 4*(l>>4) + i, col u = nt*16 + (l&15)
        const int tD = t0 + 4 * (l >> 4);
        #pragma unroll
        for (int i = 0; i < 4; ++i) {
            int t = tD + i;
            bool tv = (t < NT);
            float val = 0.f;
            #pragma unroll
            for (int nt = 0; nt < 3; ++nt) {
                float x = acc[nt][i] + kwv[nt];
                float z = (x - dmv[nt]) * drs[nt];
                float p = 1.f / (1.f + __expf(-z));
                val += x * (dav[nt] + p * (1.f - dav[nt])) * w2v[nt];
            }
            val += __shfl_xor(val, 1);
            val += __shfl_xor(val, 2);
            val += __shfl_xor(val, 4);
            val += __shfl_xor(val, 8);
            if (ul == 0 && tv) w_s[t] = val + b2s;
        }
    }
    __syncthreads();

    // interest[e] = sum_t w[t]*ub[b,t,e]; BN1; write bf16 H row cols 0..63
    {
        const int e = tid & 63, g = tid >> 6;
        const float* ubb = P.ub + (size_t)b * NT * NE;
        float s = 0.f;
        #pragma unroll 5
        for (int t = g * 50; t < g * 50 + 50; ++t)
            s = fmaf(w_s[t], ubb[t * NE + e], s);
        red_s[tid] = s;
    }
    __syncthreads();
    if (tid < 64) {
        float tot = red_s[tid] + red_s[64 + tid] + red_s[128 + tid] + red_s[192 + tid];
        float hn = (tot - P.bn1_m[tid]) * rsqrtf(P.bn1_v[tid] + 1e-6f) * P.bn1_g[tid] + P.bn1_b[tid];
        P.Hh[((size_t)b * NTQ + tq) * 256 + tid] = f2bf(hn);
    }
}

// ---------------------------------------------------------------------------
// Kernel T: batched trunk MLP over 1600 rows. Block = 32 rows, 4 waves.
// ---------------------------------------------------------------------------
struct TParams {
    const short *Hh, *wm1f, *wm2f, *wm3f;
    const float *bm1, *bm2, *bm3;
    const float *bn2_g, *bn2_b, *bn2_m, *bn2_v;
    const float *bn3_g, *bn3_b, *bn3_m, *bn3_v;
    float* out;
};

#define LSTR 264   // bf16 row stride: 528B -> <=2-way bank aliasing (free)

__global__ __launch_bounds__(256) void trunk(TParams P) {
    __shared__ short Ha[32 * LSTR];
    __shared__ short Hb[32 * LSTR];

    const int tid = threadIdx.x;
    const int l = tid & 63, w = tid >> 6;
    const int mt = w & 1, nh = w >> 1;
    const int row0 = blockIdx.x * 32;

    {
        const bf8* src = (const bf8*)(P.Hh + (size_t)row0 * 256);
        for (int ch = tid; ch < 32 * 32; ch += 256) {
            int r = ch >> 5, c8 = ch & 31;
            *(bf8*)&Ha[r * LSTR + c8 * 8] = src[r * 32 + c8];
        }
    }
    __syncthreads();

    const int ar = mt * 16 + (l & 15);
    const int rl = mt * 16 + 4 * (l >> 4);
    const int nl = l & 15;

    // ---- layer 1: K=256, N=256 : Ha -> Hb, relu then BN2 ----
    {
        bf8 a[8];
        #pragma unroll
        for (int ks = 0; ks < 8; ++ks)
            a[ks] = *(const bf8*)&Ha[ar * LSTR + ks * 32 + 8 * (l >> 4)];
        const bf8* wf = (const bf8*)P.wm1f;
        #pragma unroll
        for (int nt0 = 0; nt0 < 8; ++nt0) {
            int nt = nh * 8 + nt0;
            f4 acc; acc[0]=0.f; acc[1]=0.f; acc[2]=0.f; acc[3]=0.f;
            #pragma unroll
            for (int ks = 0; ks < 8; ++ks)
                acc = __builtin_amdgcn_mfma_f32_16x16x32_bf16(a[ks], wf[(nt * 8 + ks) * 64 + l], acc, 0, 0, 0);
            int n = nt * 16 + nl;
            float g1 = P.bn2_g[n] * rsqrtf(P.bn2_v[n] + 1e-6f);
            float c1 = P.bn2_b[n] - P.bn2_m[n] * g1;
            float bias = P.bm1[n];
            #pragma unroll
            for (int i = 0; i < 4; ++i) {
                float v = fmaxf(acc[i] + bias, 0.f);
                Hb[(rl + i) * LSTR + n] = f2bf(v * g1 + c1);
            }
        }
    }
    __syncthreads();

    // ---- layer 2: K=256, N=128 : Hb -> Ha[:,0:128], relu then BN3 ----
    {
        bf8 a[8];
        #pragma unroll
        for (int ks = 0; ks < 8; ++ks)
            a[ks] = *(const bf8*)&Hb[ar * LSTR + ks * 32 + 8 * (l >> 4)];
        const bf8* wf = (const bf8*)P.wm2f;
        #pragma unroll
        for (int nt0 = 0; nt0 < 4; ++nt0) {
            int nt = nh * 4 + nt0;
            f4 acc; acc[0]=0.f; acc[1]=0.f; acc[2]=0.f; acc[3]=0.f;
            #pragma unroll
            for (int ks = 0; ks < 8; ++ks)
                acc = __builtin_amdgcn_mfma_f32_16x16x32_bf16(a[ks], wf[(nt * 8 + ks) * 64 + l], acc, 0, 0, 0);
            int n = nt * 16 + nl;
            float g1 = P.bn3_g[n] * rsqrtf(P.bn3_v[n] + 1e-6f);
            float c1 = P.bn3_b[n] - P.bn3_m[n] * g1;
            float bias = P.bm2[n];
            #pragma unroll
            for (int i = 0; i < 4; ++i) {
                float v = fmaxf(acc[i] + bias, 0.f);
                Ha[(rl + i) * LSTR + n] = f2bf(v * g1 + c1);
            }
        }
    }
    __syncthreads();

    // ---- layer 3: K=128, N=64 : Ha[:,0:128] -> out, relu ----
    {
        bf8 a[4];
        #pragma unroll
        for (int ks = 0; ks < 4; ++ks)
            a[ks] = *(const bf8*)&Ha[ar * LSTR + ks * 32 + 8 * (l >> 4)];
        const bf8* wf = (const bf8*)P.wm3f;
        #pragma unroll
        for (int nt0 = 0; nt0 < 2; ++nt0) {
            int nt = nh * 2 + nt0;
            f4 acc; acc[0]=0.f; acc[1]=0.f; acc[2]=0.f; acc[3]=0.f;
            #pragma unroll
            for (int ks = 0; ks < 4; ++ks)
                acc = __builtin_amdgcn_mfma_f32_16x16x32_bf16(a[ks], wf[(nt * 4 + ks) * 64 + l], acc, 0, 0, 0);
            int n = nt * 16 + nl;
            float bias = P.bm3[n];
            #pragma unroll
            for (int i = 0; i < 4; ++i)
                P.out[(size_t)(row0 + rl + i) * 64 + n] = fmaxf(acc[i] + bias, 0.f);
        }
    }
}

// ---------------------------------------------------------------------------
extern "C" void kernel_launch(void* const* d_in, const int* in_sizes, int n_in,
                              void* d_out, int out_size, void* d_ws, size_t ws_size,
                              hipStream_t stream) {
    (void)in_sizes; (void)n_in; (void)out_size; (void)ws_size;

    const float* ub         = (const float*)d_in[0];
    const float* it         = (const float*)d_in[1];
    const float* up         = (const float*)d_in[2];
    const float* cx         = (const float*)d_in[3];
    const float* W1         = (const float*)d_in[4];
    const float* b1         = (const float*)d_in[5];
    const float* dice_alpha = (const float*)d_in[6];
    const float* dice_mean  = (const float*)d_in[7];
    const float* dice_var   = (const float*)d_in[8];
    const float* W2         = (const float*)d_in[9];
    const float* b2         = (const float*)d_in[10];
    const float* bn1_g      = (const float*)d_in[11];
    const float* bn1_b      = (const float*)d_in[12];
    const float* bn1_m      = (const float*)d_in[13];
    const float* bn1_v      = (const float*)d_in[14];
    const float* Wm1        = (const float*)d_in[15];
    const float* bm1        = (const float*)d_in[16];
    const float* bn2_g      = (const float*)d_in[17];
    const float* bn2_b      = (const float*)d_in[18];
    const float* bn2_m      = (const float*)d_in[19];
    const float* bn2_v      = (const float*)d_in[20];
    const float* Wm2        = (const float*)d_in[21];
    const float* bm2        = (const float*)d_in[22];
    const float* bn3_g      = (const float*)d_in[23];
    const float* bn3_b      = (const float*)d_in[24];
    const float* bn3_m      = (const float*)d_in[25];
    const float* bn3_v      = (const float*)d_in[26];
    const float* Wm3        = (const float*)d_in[27];
    const float* bm3        = (const float*)d_in[28];

    float* kW  = (float*)d_ws + KW_F32;
    short* wsb = (short*)((float*)d_ws + BF_BASE);
    short* w1f  = wsb + W1F_OFF;
    short* wm1f = wsb + WM1F_OFF;
    short* wm2f = wsb + WM2F_OFF;
    short* wm3f = wsb + WM3F_OFF;
    short* Hh   = wsb + HH_OFF;

    const int prep_total = NB * NTQ * NU + 6144 + 65536 + 32768 + 8192 + NROW * 192; // 477440
    prep<<<(prep_total + 255) / 256, 256, 0, stream>>>(
        it, up, cx, W1, b1, Wm1, Wm2, Wm3,
        bn1_g, bn1_b, bn1_m, bn1_v,
        kW, w1f, wm1f, wm2f, wm3f, Hh);

    AParams A;
    A.ub = ub; A.it = it; A.kW = kW;
    A.W2 = W2; A.b2 = b2; A.da = dice_alpha; A.dm = dice_mean; A.dv = dice_var;
    A.bn1_g = bn1_g; A.bn1_b = bn1_b; A.bn1_m = bn1_m; A.bn1_v = bn1_v;
    A.w1f = w1f; A.Hh = Hh;
    attn<<<dim3(NTQ, NB), 256, 0, stream>>>(A);

    TParams T;
    T.Hh = Hh; T.wm1f = wm1f; T.wm2f = wm2f; T.wm3f = wm3f;
    T.bm1 = bm1; T.bm2 = bm2; T.bm3 = bm3;
    T.bn2_g = bn2_g; T.bn2_b = bn2_b; T.bn2_m = bn2_m; T.bn2_v = bn2_v;
    T.bn3_g = bn3_g; T.bn3_b = bn3_b; T.bn3_m = bn3_m; T.bn3_v = bn3_v;
    T.out = (float*)d_out;
    trunk<<<NROW / 32, 256, 0, stream>>>(T);
}

// Round 4
// 153.085 us; speedup vs baseline: 1.5503x; 1.1984x over previous
//
#include <hip/hip_runtime.h>
#include <hip/hip_bf16.h>
#include <math.h>

#define NB  32
#define NT  200
#define NTQ 50
#define NE  64
#define NP  128
#define NC  64
#define NU  36
#define NROW (NB * NTQ)   // 1600

typedef __attribute__((ext_vector_type(8))) short bf8;   // 8 bf16 in 4 VGPRs
typedef __attribute__((ext_vector_type(4))) float f4;

// ---- ws layout ----
// f32 region:
//   kW  : [NB*NTQ*NU] = 57600    @ 0   (includes b1)
// bf16 region (base = 57600 f32 elems):
//   w1f : [3][4][64][8]          @ 0       (6144)   extended-K B frags
//   wm1f: [16*8][64][8]          @ 6144    (65536)
//   wm2f: [8*8][64][8]           @ 71680   (32768)
//   wm3f: [4*4][64][8]           @ 104448  (8192)
//   Hh  : [1600][64]             @ 112640  (102400)  attn interest (bn1'd), bf16
#define KW_F32   0
#define BF_BASE  57600
#define W1F_OFF  0
#define WM1F_OFF 6144
#define WM2F_OFF 71680
#define WM3F_OFF 104448
#define HH_OFF   112640

__device__ __forceinline__ short f2bf(float x) {
    __hip_bfloat16 h = __float2bfloat16(x);
    return __builtin_bit_cast(short, h);
}

// ---------------------------------------------------------------------------
// Kernel P: precompute.
//   J2: kW (57600) -- k@(W1b-W1c) + b1
//   J3: w1f (6144) -- extended-K [ (W1a+W1c) ; W1d ] fragments (u padded to 48)
//   J4/5/6: trunk weight fragments
// ---------------------------------------------------------------------------
__device__ __forceinline__ void pack_frag(int j, const float* W, int N, int ksc, short* dst) {
    int i    = j & 7;
    int lane = (j >> 3) & 63;
    int tile = j >> 9;
    int ks = tile % ksc;
    int nt = tile / ksc;
    int k = ks * 32 + 8 * (lane >> 4) + i;
    int n = nt * 16 + (lane & 15);
    dst[j] = f2bf(W[k * N + n]);
}

__global__ __launch_bounds__(256) void prep(
    const float* __restrict__ it,
    const float* __restrict__ W1, const float* __restrict__ b1,
    const float* __restrict__ Wm1, const float* __restrict__ Wm2, const float* __restrict__ Wm3,
    float* __restrict__ kW,
    short* __restrict__ w1f, short* __restrict__ wm1f,
    short* __restrict__ wm2f, short* __restrict__ wm3f)
{
    int idx = blockIdx.x * 256 + threadIdx.x;
    if (idx < NB * NTQ * NU) {                      // J2: kW (+ b1)
        int u = idx % NU, row = idx / NU;
        const float* k = it + row * NE;
        float acc = b1[u];
        #pragma unroll 4
        for (int e = 0; e < NE; ++e)
            acc = fmaf(k[e], W1[(64 + e) * NU + u] - W1[(128 + e) * NU + u], acc);
        kW[idx] = acc;
        return;
    }
    idx -= NB * NTQ * NU;
    if (idx < 6144) {                               // J3: extended-K W1 frags
        int i = idx & 7, lane = (idx >> 3) & 63, tile = idx >> 9;
        int ks = tile & 3, nt = tile >> 2;
        int kk = ks * 32 + 8 * (lane >> 4) + i;     // 0..127
        int n  = nt * 16 + (lane & 15);             // u in 0..47
        float v = 0.f;
        if (n < NU) {
            v = W1[(128 + kk) * NU + n];            // kk<64: W1c ; kk>=64: W1d
            if (kk < 64) v += W1[kk * NU + n];      // + W1a
        }
        w1f[idx] = f2bf(v);
        return;
    }
    idx -= 6144;
    if (idx < 65536) { pack_frag(idx, Wm1, 256, 8, wm1f); return; }
    idx -= 65536;
    if (idx < 32768) { pack_frag(idx, Wm2, 128, 8, wm2f); return; }
    idx -= 32768;
    if (idx < 8192)  { pack_frag(idx, Wm3,  64, 4, wm3f); return; }
}

// ---------------------------------------------------------------------------
// Kernel A: attention with extended-K MFMA (K=128: [q | q*k]) + dice + W2,
// interest reduction, BN1 -> Hh (1600 x 64 bf16). One block per (tq, b).
// ---------------------------------------------------------------------------
struct AParams {
    const float *ub, *it, *kW, *W2, *b2, *da, *dm, *dv;
    const float *bn1_g, *bn1_b, *bn1_m, *bn1_v;
    const short *w1f;
    short* Hh;
};

__global__ __launch_bounds__(256) void attn(AParams P) {
    __shared__ float w_s[NT];
    __shared__ float red_s[256];

    const int tid = threadIdx.x;
    const int l = tid & 63, w = tid >> 6;
    const int tq = blockIdx.x, b = blockIdx.y;

    // B-fragments (12 x bf8 = 48 VGPR), live for the whole kernel
    bf8 bfr[3][4];
    {
        const bf8* wf = (const bf8*)P.w1f;
        #pragma unroll
        for (int nt = 0; nt < 3; ++nt)
            #pragma unroll
            for (int ks = 0; ks < 4; ++ks)
                bfr[nt][ks] = wf[(nt * 4 + ks) * 64 + l];
    }

    // this lane's it[e] values at A-frag k positions: e = ks*32 + 8*(l>>4) + i
    float itv[2][8];
    {
        const float* itr = P.it + ((size_t)b * NTQ + tq) * NE;
        #pragma unroll
        for (int ks = 0; ks < 2; ++ks) {
            int e0 = ks * 32 + 8 * (l >> 4);
            f4 v0 = *(const f4*)(itr + e0);
            f4 v1 = *(const f4*)(itr + e0 + 4);
            #pragma unroll
            for (int i = 0; i < 4; ++i) { itv[ks][i] = v0[i]; itv[ks][4 + i] = v1[i]; }
        }
    }

    // per-u (output column) constants
    const int ul = l & 15;
    float kwv[3], dmv[3], drs[3], dav[3], w2v[3];
    {
        const float* kwr = P.kW + ((size_t)b * NTQ + tq) * NU;
        #pragma unroll
        for (int nt = 0; nt < 3; ++nt) {
            int u = nt * 16 + ul;
            bool v = (u < NU);
            int uc = v ? u : (NU - 1);
            kwv[nt] = v ? kwr[uc] : 0.f;
            dmv[nt] = P.dm[uc];
            drs[nt] = rsqrtf(P.dv[uc] + 1e-6f);
            dav[nt] = P.da[uc];
            w2v[nt] = v ? P.W2[uc] : 0.f;
        }
    }
    const float b2s = P.b2[0];

    for (int tt = w; tt < 13; tt += 4) {
        const int t0 = tt * 16;
        const int tA = t0 + (l & 15);           // A-frag row

        bf8 aq[2], ap[2];
        if (tA < NT) {
            const float* ubr = P.ub + ((size_t)b * NT + tA) * NE;
            #pragma unroll
            for (int ks = 0; ks < 2; ++ks) {
                int e0 = ks * 32 + 8 * (l >> 4);
                f4 u0 = *(const f4*)(ubr + e0);
                f4 u1 = *(const f4*)(ubr + e0 + 4);
                #pragma unroll
                for (int i = 0; i < 4; ++i) {
                    aq[ks][i]     = f2bf(u0[i]);
                    aq[ks][4 + i] = f2bf(u1[i]);
                    ap[ks][i]     = f2bf(u0[i] * itv[ks][i]);
                    ap[ks][4 + i] = f2bf(u1[i] * itv[ks][4 + i]);
                }
            }
        } else {
            #pragma unroll
            for (int ks = 0; ks < 2; ++ks)
                #pragma unroll
                for (int i = 0; i < 8; ++i) { aq[ks][i] = 0; ap[ks][i] = 0; }
        }

        f4 acc[3];
        #pragma unroll
        for (int nt = 0; nt < 3; ++nt) { acc[nt][0]=0.f; acc[nt][1]=0.f; acc[nt][2]=0.f; acc[nt][3]=0.f; }
        #pragma unroll
        for (int nt = 0; nt < 3; ++nt) {
            acc[nt] = __builtin_amdgcn_mfma_f32_16x16x32_bf16(aq[0], bfr[nt][0], acc[nt], 0, 0, 0);
            acc[nt] = __builtin_amdgcn_mfma_f32_16x16x32_bf16(aq[1], bfr[nt][1], acc[nt], 0, 0, 0);
            acc[nt] = __builtin_amdgcn_mfma_f32_16x16x32_bf16(ap[0], bfr[nt][2], acc[nt], 0, 0, 0);
            acc[nt] = __builtin_amdgcn_mfma_f32_16x16x32_bf16(ap[1], bfr[nt][3], acc[nt], 0, 0, 0);
        }

        // epilogue: D row = t0 + 4*(l>>4) + i, col u = nt*16 + (l&15)
        const int tD = t0 + 4 * (l >> 4);
        #pragma unroll
        for (int i = 0; i < 4; ++i) {
            int t = tD + i;
            bool tv = (t < NT);
            float val = 0.f;
            #pragma unroll
            for (int nt = 0; nt < 3; ++nt) {
                float x = acc[nt][i] + kwv[nt];
                float z = (x - dmv[nt]) * drs[nt];
                float p = 1.f / (1.f + __expf(-z));
                val += x * (dav[nt] + p * (1.f - dav[nt])) * w2v[nt];
            }
            val += __shfl_xor(val, 1);
            val += __shfl_xor(val, 2);
            val += __shfl_xor(val, 4);
            val += __shfl_xor(val, 8);
            if (ul == 0 && tv) w_s[t] = val + b2s;
        }
    }
    __syncthreads();

    // interest[e] = sum_t w[t]*ub[b,t,e]; BN1; write bf16 Hh row (64 wide)
    {
        const int e = tid & 63, g = tid >> 6;
        const float* ubb = P.ub + (size_t)b * NT * NE;
        float s = 0.f;
        #pragma unroll 5
        for (int t = g * 50; t < g * 50 + 50; ++t)
            s = fmaf(w_s[t], ubb[t * NE + e], s);
        red_s[tid] = s;
    }
    __syncthreads();
    if (tid < 64) {
        float tot = red_s[tid] + red_s[64 + tid] + red_s[128 + tid] + red_s[192 + tid];
        float hn = (tot - P.bn1_m[tid]) * rsqrtf(P.bn1_v[tid] + 1e-6f) * P.bn1_g[tid] + P.bn1_b[tid];
        P.Hh[((size_t)b * NTQ + tq) * 64 + tid] = f2bf(hn);
    }
}

// ---------------------------------------------------------------------------
// Kernel T: batched trunk MLP. 100 blocks x 16 rows; 4 waves, wave w owns
// N-quarter. Staging computes bn1(profile||context) cols on the fly.
// ---------------------------------------------------------------------------
struct TParams {
    const short *Hh, *wm1f, *wm2f, *wm3f;
    const float *up, *cx;
    const float *bn1_g, *bn1_b, *bn1_m, *bn1_v;
    const float *bm1, *bm2, *bm3;
    const float *bn2_g, *bn2_b, *bn2_m, *bn2_v;
    const float *bn3_g, *bn3_b, *bn3_m, *bn3_v;
    float* out;
};

#define LSTR 264   // bf16 row stride: 528B -> <=2-way bank aliasing (free)

__global__ __launch_bounds__(256) void trunk(TParams P) {
    __shared__ short Ha[16 * LSTR];
    __shared__ short Hb[16 * LSTR];

    const int tid = threadIdx.x;
    const int l = tid & 63, w = tid >> 6;
    const int row0 = blockIdx.x * 16;

    // stage cols 0..63 from Hh (attn output, already bn1'd)
    {
        const bf8* src = (const bf8*)(P.Hh + (size_t)row0 * 64);
        for (int ch = tid; ch < 16 * 8; ch += 256) {
            int r = ch >> 3, c8 = ch & 7;
            *(bf8*)&Ha[r * LSTR + c8 * 8] = src[r * 8 + c8];
        }
    }
    // stage cols 64..255 = bn1(profile || context), computed on the fly
    for (int ch = tid; ch < 16 * 192; ch += 256) {
        int r = ch / 192, c = ch % 192;
        int col = 64 + c;
        int b = (row0 + r) / NTQ;
        float val = (c < NP) ? P.up[b * NP + c] : P.cx[b * NC + (c - NP)];
        float hn = (val - P.bn1_m[col]) * rsqrtf(P.bn1_v[col] + 1e-6f)
                   * P.bn1_g[col] + P.bn1_b[col];
        Ha[r * LSTR + col] = f2bf(hn);
    }
    __syncthreads();

    const int ar = l & 15;            // A-frag row
    const int rl = 4 * (l >> 4);      // D row base
    const int nl = l & 15;            // D col within n-tile

    // ---- layer 1: K=256, N=256 : Ha -> Hb, relu then BN2 ----
    {
        bf8 a[8];
        #pragma unroll
        for (int ks = 0; ks < 8; ++ks)
            a[ks] = *(const bf8*)&Ha[ar * LSTR + ks * 32 + 8 * (l >> 4)];
        const bf8* wf = (const bf8*)P.wm1f;
        #pragma unroll
        for (int nt0 = 0; nt0 < 4; ++nt0) {
            int nt = w * 4 + nt0;
            f4 acc; acc[0]=0.f; acc[1]=0.f; acc[2]=0.f; acc[3]=0.f;
            #pragma unroll
            for (int ks = 0; ks < 8; ++ks)
                acc = __builtin_amdgcn_mfma_f32_16x16x32_bf16(a[ks], wf[(nt * 8 + ks) * 64 + l], acc, 0, 0, 0);
            int n = nt * 16 + nl;
            float g1 = P.bn2_g[n] * rsqrtf(P.bn2_v[n] + 1e-6f);
            float c1 = P.bn2_b[n] - P.bn2_m[n] * g1;
            float bias = P.bm1[n];
            #pragma unroll
            for (int i = 0; i < 4; ++i) {
                float v = fmaxf(acc[i] + bias, 0.f);
                Hb[(rl + i) * LSTR + n] = f2bf(v * g1 + c1);
            }
        }
    }
    __syncthreads();

    // ---- layer 2: K=256, N=128 : Hb -> Ha[:,0:128], relu then BN3 ----
    {
        bf8 a[8];
        #pragma unroll
        for (int ks = 0; ks < 8; ++ks)
            a[ks] = *(const bf8*)&Hb[ar * LSTR + ks * 32 + 8 * (l >> 4)];
        const bf8* wf = (const bf8*)P.wm2f;
        #pragma unroll
        for (int nt0 = 0; nt0 < 2; ++nt0) {
            int nt = w * 2 + nt0;
            f4 acc; acc[0]=0.f; acc[1]=0.f; acc[2]=0.f; acc[3]=0.f;
            #pragma unroll
            for (int ks = 0; ks < 8; ++ks)
                acc = __builtin_amdgcn_mfma_f32_16x16x32_bf16(a[ks], wf[(nt * 8 + ks) * 64 + l], acc, 0, 0, 0);
            int n = nt * 16 + nl;
            float g1 = P.bn3_g[n] * rsqrtf(P.bn3_v[n] + 1e-6f);
            float c1 = P.bn3_b[n] - P.bn3_m[n] * g1;
            float bias = P.bm2[n];
            #pragma unroll
            for (int i = 0; i < 4; ++i) {
                float v = fmaxf(acc[i] + bias, 0.f);
                Ha[(rl + i) * LSTR + n] = f2bf(v * g1 + c1);
            }
        }
    }
    __syncthreads();

    // ---- layer 3: K=128, N=64 : Ha[:,0:128] -> out, relu ----
    {
        bf8 a[4];
        #pragma unroll
        for (int ks = 0; ks < 4; ++ks)
            a[ks] = *(const bf8*)&Ha[ar * LSTR + ks * 32 + 8 * (l >> 4)];
        const bf8* wf = (const bf8*)P.wm3f;
        {
            int nt = w;
            f4 acc; acc[0]=0.f; acc[1]=0.f; acc[2]=0.f; acc[3]=0.f;
            #pragma unroll
            for (int ks = 0; ks < 4; ++ks)
                acc = __builtin_amdgcn_mfma_f32_16x16x32_bf16(a[ks], wf[(nt * 4 + ks) * 64 + l], acc, 0, 0, 0);
            int n = nt * 16 + nl;
            float bias = P.bm3[n];
            #pragma unroll
            for (int i = 0; i < 4; ++i)
                P.out[(size_t)(row0 + rl + i) * 64 + n] = fmaxf(acc[i] + bias, 0.f);
        }
    }
}

// ---------------------------------------------------------------------------
extern "C" void kernel_launch(void* const* d_in, const int* in_sizes, int n_in,
                              void* d_out, int out_size, void* d_ws, size_t ws_size,
                              hipStream_t stream) {
    (void)in_sizes; (void)n_in; (void)out_size; (void)ws_size;

    const float* ub         = (const float*)d_in[0];
    const float* it         = (const float*)d_in[1];
    const float* up         = (const float*)d_in[2];
    const float* cx         = (const float*)d_in[3];
    const float* W1         = (const float*)d_in[4];
    const float* b1         = (const float*)d_in[5];
    const float* dice_alpha = (const float*)d_in[6];
    const float* dice_mean  = (const float*)d_in[7];
    const float* dice_var   = (const float*)d_in[8];
    const float* W2         = (const float*)d_in[9];
    const float* b2         = (const float*)d_in[10];
    const float* bn1_g      = (const float*)d_in[11];
    const float* bn1_b      = (const float*)d_in[12];
    const float* bn1_m      = (const float*)d_in[13];
    const float* bn1_v      = (const float*)d_in[14];
    const float* Wm1        = (const float*)d_in[15];
    const float* bm1        = (const float*)d_in[16];
    const float* bn2_g      = (const float*)d_in[17];
    const float* bn2_b      = (const float*)d_in[18];
    const float* bn2_m      = (const float*)d_in[19];
    const float* bn2_v      = (const float*)d_in[20];
    const float* Wm2        = (const float*)d_in[21];
    const float* bm2        = (const float*)d_in[22];
    const float* bn3_g      = (const float*)d_in[23];
    const float* bn3_b      = (const float*)d_in[24];
    const float* bn3_m      = (const float*)d_in[25];
    const float* bn3_v      = (const float*)d_in[26];
    const float* Wm3        = (const float*)d_in[27];
    const float* bm3        = (const float*)d_in[28];

    float* kW  = (float*)d_ws + KW_F32;
    short* wsb = (short*)((float*)d_ws + BF_BASE);
    short* w1f  = wsb + W1F_OFF;
    short* wm1f = wsb + WM1F_OFF;
    short* wm2f = wsb + WM2F_OFF;
    short* wm3f = wsb + WM3F_OFF;
    short* Hh   = wsb + HH_OFF;

    const int prep_total = NB * NTQ * NU + 6144 + 65536 + 32768 + 8192; // 170240
    prep<<<(prep_total + 255) / 256, 256, 0, stream>>>(
        it, W1, b1, Wm1, Wm2, Wm3,
        kW, w1f, wm1f, wm2f, wm3f);

    AParams A;
    A.ub = ub; A.it = it; A.kW = kW;
    A.W2 = W2; A.b2 = b2; A.da = dice_alpha; A.dm = dice_mean; A.dv = dice_var;
    A.bn1_g = bn1_g; A.bn1_b = bn1_b; A.bn1_m = bn1_m; A.bn1_v = bn1_v;
    A.w1f = w1f; A.Hh = Hh;
    attn<<<dim3(NTQ, NB), 256, 0, stream>>>(A);

    TParams T;
    T.Hh = Hh; T.wm1f = wm1f; T.wm2f = wm2f; T.wm3f = wm3f;
    T.up = up; T.cx = cx;
    T.bn1_g = bn1_g; T.bn1_b = bn1_b; T.bn1_m = bn1_m; T.bn1_v = bn1_v;
    T.bm1 = bm1; T.bm2 = bm2; T.bm3 = bm3;
    T.bn2_g = bn2_g; T.bn2_b = bn2_b; T.bn2_m = bn2_m; T.bn2_v = bn2_v;
    T.bn3_g = bn3_g; T.bn3_b = bn3_b; T.bn3_m = bn3_m; T.bn3_v = bn3_v;
    T.out = (float*)d_out;
    trunk<<<NROW / 16, 256, 0, stream>>>(T);
}